// Round 1
// baseline (610.840 us; speedup 1.0000x reference)
//
#include <hip/hip_runtime.h>

// SpectralConv2d as bf16-MFMA GEMM stages. B=16, Ci=Co=64, S=256, m1=m2=32 -> 63x32 modes.
// R1: (a) k_wexp deleted -- k_s3 expands packed weights from Wtmp in-LDS (saves 132 MB traffic);
//     (b) k_s4+k_s5 fused into k_s45 -- Y1 lives in LDS, never in global (saves 67 MB).

typedef __attribute__((ext_vector_type(8))) short bfrag8;   // 8 bf16 = 16B
typedef __attribute__((ext_vector_type(4))) float facc4;    // MFMA accumulator

// ---- workspace layout (bf16-element offsets) ----
#define F1F_O 0u            // [8 ks][4 nt][64 lane][8 j]        16384
#define T2F_O 16384u        // [8 mt][16 ks][64][8]              65536
#define T4F_O 81920u        // [32 mt][4 ks][64][8]              65536
#define F5F_O 147456u       // [2 ks][16 nt][64][8]              16384
#define WF_O  163840u       // region reused: Wtmp uint[2016][4096], wpre -> s3 lifetime
#define X1T_O 33193984u     // [1024 bi][32 n][512 kk]           16777216
#define C2_O  49971200u     // [1024 bi][128 m][32 n]            4194304
#define X2M_O 54165504u     // [2016 mode][16 b][128 ic]         4128768
// overlays (stream-ordered lifetimes):
#define WTMP_O WF_O                   // uint[2016 mode][4096 io] (r|i<<16), read by s3
#define C3_O  X1T_O                   // [2016 mode][16 b][128 nc] after s2
#define X3T_O (X1T_O + 4128768u)      // [1024 bo][32 kx][128 kk]

#define TWO_PI_256 0.0245436926f

__device__ __forceinline__ unsigned short f2bf(float f) {
  unsigned u = __float_as_uint(f);
  u += 0x7fffu + ((u >> 16) & 1u);          // RNE
  return (unsigned short)(u >> 16);
}
__device__ __forceinline__ bfrag8 ldf(const unsigned short* p) {
  return *(const bfrag8*)p;
}
// 16B fragment from 8B-aligned LDS (stride-36 rows): two b64 reads
__device__ __forceinline__ bfrag8 ld8u2(const unsigned short* p) {
  union { uint2 u2[2]; bfrag8 f; } v;
  v.u2[0] = *(const uint2*)(p);
  v.u2[1] = *(const uint2*)(p + 4);
  return v.f;
}

// ---------- build constant DFT matrices in fragment-linear layout ----------
__global__ void k_tables(unsigned short* ws) {
  int t = threadIdx.x;
  for (int q = 0; q < 4; ++q) {
    int idx = blockIdx.x * 1024 + q * 256 + t;
    float val = 0.f; unsigned dst;
    if (idx < 16384) {                       // F1f: B[k=x][n], fwd row rDFT, /256
      int u = idx, j = u & 7, lane = (u >> 3) & 63, nt = (u >> 9) & 3, ks = u >> 11;
      int k = ks * 32 + (lane >> 4) * 8 + j, n = nt * 16 + (lane & 15);
      if (n < 32) val =  cosf((float)((k * n) & 255) * TWO_PI_256) * (1.f / 256.f);
      else        val = -sinf((float)((k * (n - 32)) & 255) * TWO_PI_256) * (1.f / 256.f);
      dst = F1F_O + (unsigned)idx;
    } else if (idx < 81920) {                // T2f: A[m][kk], fwd col DFT (real form)
      int u = idx - 16384, j = u & 7, lane = (u >> 3) & 63, ks = (u >> 9) & 15, mt = u >> 13;
      int m = mt * 16 + (lane & 15), k = ks * 32 + (lane >> 4) * 8 + j;
      if (m < 126) {
        int ky = m < 63 ? m : m - 63;
        int y = k & 255, f = (ky + 225) & 255;
        float ang = (float)((y * f) & 255) * TWO_PI_256;
        float c = cosf(ang), s = sinf(ang);
        val = (m < 63) ? ((k < 256) ? c : s) : ((k < 256) ? -s : c);
      }
      dst = T2F_O + (unsigned)u;
    } else if (idx < 147456) {               // T4f: A[m][kk], inv col DFT
      int u = idx - 81920, j = u & 7, lane = (u >> 3) & 63, ks = (u >> 9) & 3, mt = u >> 11;
      int m = mt * 16 + (lane & 15), k = ks * 32 + (lane >> 4) * 8 + j;
      if (k < 126) {
        int ky = k < 63 ? k : k - 63;
        int y = m & 255, f = (ky + 225) & 255;
        float ang = (float)((y * f) & 255) * TWO_PI_256;
        float c = cosf(ang), s = sinf(ang);
        val = (m < 256) ? ((k < 63) ? c : -s) : ((k < 63) ? s : c);
      }
      dst = T4F_O + (unsigned)u;
    } else {                                 // F5f: B[k][n=x], inv row irDFT, /256
      int u = idx - 147456, j = u & 7, lane = (u >> 3) & 63, nt = (u >> 9) & 15, ks = u >> 13;
      int k = ks * 32 + (lane >> 4) * 8 + j, n = nt * 16 + (lane & 15);
      int kf = k & 31;
      float ang = (float)((kf * n) & 255) * TWO_PI_256;
      if (k < 32) val = ((kf == 0) ? 1.f : 2.f) * cosf(ang) * (1.f / 256.f);
      else        val = (kf == 0) ? 0.f : -2.f * sinf(ang) * (1.f / 256.f);
      dst = F5F_O + (unsigned)u;
    }
    ws[dst] = f2bf(val);
  }
}

// ---------- weight build: coalesced read -> Wtmp[mode][io] packed (r,i) ----------
__global__ void k_wpre(const float* __restrict__ y0r, const float* __restrict__ y0i,
                       const float* __restrict__ ypr, const float* __restrict__ ypi,
                       const float* __restrict__ w00, unsigned short* ws) {
  unsigned* Wtmp = (unsigned*)(ws + WTMP_O);
  int chunk = blockIdx.x >> 4, kq = blockIdx.x & 15;
  int io = chunk * 256 + threadIdx.x;
  int ky0 = kq * 4, nky = (kq == 15) ? 3 : 4;
  const float* pr = ypr + (size_t)io * 1953 + (size_t)ky0 * 31;
  const float* pi_ = ypi + (size_t)io * 1953 + (size_t)ky0 * 31;
  for (int q = 0; q < nky; ++q) {
    int ky = ky0 + q;
#pragma unroll
    for (int kxs = 0; kxs < 31; ++kxs) {
      float r = pr[q * 31 + kxs], im = pi_[q * 31 + kxs];
      Wtmp[(unsigned)(ky * 32 + kxs + 1) * 4096u + io] =
          (unsigned)f2bf(r) | ((unsigned)f2bf(im) << 16);
    }
  }
  if (kq == 0) {                             // col0: y0 / w00 / conj(flip(y0))
    float rr[31], ii[31];
#pragma unroll
    for (int j = 0; j < 31; ++j) { rr[j] = y0r[io * 31 + j]; ii[j] = y0i[io * 31 + j]; }
    float w0 = w00[io];
    for (int ky = 0; ky < 63; ++ky) {
      float r, im;
      if (ky < 31)       { r = rr[ky];      im = ii[ky]; }
      else if (ky == 31) { r = w0;          im = 0.f; }
      else               { r = rr[62 - ky]; im = -ii[62 - ky]; }
      Wtmp[(unsigned)(ky * 32) * 4096u + io] =
          (unsigned)f2bf(r) | ((unsigned)f2bf(im) << 16);
    }
  }
}

// ---------- stage 1: row rDFT.  C1 = bf16(x) (128x256) * F1 (256x64) -> X1t ----------
__global__ void k_s1(const float* __restrict__ x, unsigned short* ws) {
  __shared__ unsigned short F1s[16384];
  __shared__ unsigned short As[128 * 40];     // pad 32->40 (16B-aligned rows, conflict-free)
  const unsigned short* F1g = ws + F1F_O;
  unsigned short* X1t = ws + X1T_O;
  int t = threadIdx.x;
  int bi = blockIdx.x >> 1, y0 = (blockIdx.x & 1) * 128;
#pragma unroll
  for (int q = 0; q < 8; ++q)
    ((uint4*)F1s)[q * 256 + t] = ((const uint4*)F1g)[q * 256 + t];
  int lane = t & 63, w = t >> 6, quad = lane >> 4, nlo = lane & 15;
  int mt0 = w * 2;
  facc4 acc[2][4];
#pragma unroll
  for (int a = 0; a < 2; ++a)
#pragma unroll
    for (int b = 0; b < 4; ++b) acc[a][b] = (facc4){0.f, 0.f, 0.f, 0.f};
  const float* img = x + (size_t)bi * 65536 + (size_t)y0 * 256;
  for (int ks = 0; ks < 8; ++ks) {
    __syncthreads();
#pragma unroll
    for (int q = 0; q < 4; ++q) {             // stage 128x32 fp32 -> bf16 LDS
      int flat = q * 1024 + t * 4;
      int r = flat >> 5, cc = flat & 31;
      float4 v = *(const float4*)(img + r * 256 + ks * 32 + cc);
      unsigned short b4[4] = { f2bf(v.x), f2bf(v.y), f2bf(v.z), f2bf(v.w) };
      *(uint2*)(As + r * 40 + cc) = *(uint2*)b4;
    }
    __syncthreads();
    bfrag8 a0 = *(bfrag8*)(As + (mt0 * 16 + nlo) * 40 + quad * 8);
    bfrag8 a1 = *(bfrag8*)(As + ((mt0 + 1) * 16 + nlo) * 40 + quad * 8);
#pragma unroll
    for (int nt = 0; nt < 4; ++nt) {
      bfrag8 b = *(bfrag8*)(F1s + ((ks * 4 + nt) * 64 + lane) * 8);
      acc[0][nt] = __builtin_amdgcn_mfma_f32_16x16x32_bf16(a0, b, acc[0][nt], 0, 0, 0);
      acc[1][nt] = __builtin_amdgcn_mfma_f32_16x16x32_bf16(a1, b, acc[1][nt], 0, 0, 0);
    }
  }
#pragma unroll
  for (int ml = 0; ml < 2; ++ml)
#pragma unroll
    for (int nt = 0; nt < 4; ++nt) {
      facc4 v = acc[ml][nt];
      int ccol = nt * 16 + nlo, n = ccol & 31, half = ccol >> 5;
      int yrow = y0 + (mt0 + ml) * 16 + quad * 4;
      unsigned short pk[4] = { f2bf(v[0]), f2bf(v[1]), f2bf(v[2]), f2bf(v[3]) };
      *(uint2*)(X1t + (unsigned)bi * 16384u + n * 512 + half * 256 + yrow) = *(uint2*)pk;
    }
}

// ---------- stage 2: col DFT.  C2 = T2 (128x512) * X1t[bi] (512x32) ----------
__global__ void k_s2(unsigned short* ws) {
  const unsigned short* T2f = ws + T2F_O;
  const unsigned short* X1t = ws + X1T_O;
  unsigned short* C2 = ws + C2_O;
  int t = threadIdx.x, lane = t & 63, w = t >> 6, quad = lane >> 4, nlo = lane & 15;
  int bi = blockIdx.x, mt0 = w * 2;
  facc4 acc[2][2];
#pragma unroll
  for (int a = 0; a < 2; ++a)
#pragma unroll
    for (int b = 0; b < 2; ++b) acc[a][b] = (facc4){0.f, 0.f, 0.f, 0.f};
  const unsigned short* Bb = X1t + (unsigned)bi * 16384u;
  for (int ks = 0; ks < 16; ++ks) {
    bfrag8 a0 = ldf(T2f + ((mt0 * 16 + ks) * 64 + lane) * 8);
    bfrag8 a1 = ldf(T2f + (((mt0 + 1) * 16 + ks) * 64 + lane) * 8);
    bfrag8 b0 = ldf(Bb + nlo * 512 + ks * 32 + quad * 8);
    bfrag8 b1 = ldf(Bb + (16 + nlo) * 512 + ks * 32 + quad * 8);
    acc[0][0] = __builtin_amdgcn_mfma_f32_16x16x32_bf16(a0, b0, acc[0][0], 0, 0, 0);
    acc[0][1] = __builtin_amdgcn_mfma_f32_16x16x32_bf16(a0, b1, acc[0][1], 0, 0, 0);
    acc[1][0] = __builtin_amdgcn_mfma_f32_16x16x32_bf16(a1, b0, acc[1][0], 0, 0, 0);
    acc[1][1] = __builtin_amdgcn_mfma_f32_16x16x32_bf16(a1, b1, acc[1][1], 0, 0, 0);
  }
#pragma unroll
  for (int ml = 0; ml < 2; ++ml)
#pragma unroll
    for (int nt = 0; nt < 2; ++nt) {
      facc4 v = acc[ml][nt];
      int n = nt * 16 + nlo, mb = (mt0 + ml) * 16 + quad * 4;
#pragma unroll
      for (int r = 0; r < 4; ++r)
        C2[(unsigned)bi * 4096u + (mb + r) * 32 + n] = f2bf(v[r]);
    }
}

// ---------- transpose 1 (LDS-tiled): C2[bi][m][n] -> X2m[mode][b][ic] ----------
__global__ void k_t1(unsigned short* ws) {
  __shared__ unsigned short lds[512 * 36];    // [half(2)][bloc(4)][i(64)] rows x 32 kx, pad 36
  const unsigned short* C2 = ws + C2_O;
  unsigned short* X2m = ws + X2M_O;
  int ky = blockIdx.x >> 2, b0 = (blockIdx.x & 3) * 4;
  int t = threadIdx.x;
#pragma unroll
  for (int rr = 0; rr < 2; ++rr) {
    int R = rr * 256 + t;
    int half = R >> 8, bloc = (R >> 6) & 3, i = R & 63;
    const uint2* src2 = (const uint2*)(C2 + (unsigned)((b0 + bloc) * 64 + i) * 4096u
                                          + (half * 63 + ky) * 32);
    uint2* d2 = (uint2*)(lds + R * 36);
#pragma unroll
    for (int c = 0; c < 8; ++c) d2[c] = src2[c];
  }
  __syncthreads();
#pragma unroll
  for (int it = 0; it < 8; ++it) {
    int flat = (it * 256 + t) * 8;            // [kx(32)][bloc(4)][ic(128)]
    int kx = flat >> 9, bloc = (flat >> 7) & 3, ic0 = flat & 127;
    unsigned short outv[8];
#pragma unroll
    for (int j = 0; j < 8; ++j) {
      int ic = ic0 + j, i = ic & 63, half = ic >> 6;
      outv[j] = lds[(half * 256 + bloc * 64 + i) * 36 + kx];
    }
    *(uint4*)(X2m + (unsigned)(ky * 32 + kx) * 2048u + (b0 + bloc) * 128 + ic0) = *(uint4*)outv;
  }
}

// ---------- stage 3 (fused wexp): C3 = X2m[mode] (16x128) * expand(Wtmp[mode]) (128x128) ----------
__global__ void k_s3(unsigned short* ws) {
  __shared__ unsigned lds[64 * 65];           // [i][o] pad 64->65: conflict-free
  const unsigned short* X2m = ws + X2M_O;
  const unsigned* Wtmp = (const unsigned*)(ws + WTMP_O);
  unsigned short* C3 = ws + C3_O;
  int t = threadIdx.x, lane = t & 63, w = t >> 6, quad = lane >> 4, nlo = lane & 15;
  int nt0 = w * 2;
  int mode = blockIdx.x;
#pragma unroll
  for (int q = 0; q < 4; ++q) {               // stage 16KB packed weights, coalesced
    int io = q * 1024 + t * 4;
    uint4 vv = *(const uint4*)(Wtmp + (unsigned)mode * 4096u + io);
    unsigned base = (unsigned)(io >> 6) * 65u + (io & 63);
    lds[base] = vv.x; lds[base + 1] = vv.y; lds[base + 2] = vv.z; lds[base + 3] = vv.w;
  }
  __syncthreads();
  facc4 acc0 = (facc4){0.f, 0.f, 0.f, 0.f}, acc1 = acc0;
  const unsigned short* Am = X2m + (unsigned)mode * 2048u;
#pragma unroll
  for (int ks = 0; ks < 4; ++ks) {            // B[k][n] = [[R,I],[-I,R]] quadrants of W
    bfrag8 a = ldf(Am + nlo * 128 + ks * 32 + quad * 8);
    bfrag8 b0, b1;
#pragma unroll
    for (int f = 0; f < 2; ++f) {
      int n = (nt0 + f) * 16 + nlo, o = n & 63, oh = n >> 6;   // oh wave-uniform
#pragma unroll
      for (int j = 0; j < 8; ++j) {
        int i = (ks & 1) * 32 + quad * 8 + j;                  // i = k & 63; kh = ks>>1
        unsigned pk = lds[i * 65 + o];
        unsigned short re = (unsigned short)(pk & 0xffffu);
        unsigned short im = (unsigned short)(pk >> 16);
        unsigned short ev = (ks < 2) ? (oh == 0 ? re : im)
                                     : (oh == 0 ? (unsigned short)(im ^ 0x8000u) : re);
        if (f == 0) b0[j] = (short)ev; else b1[j] = (short)ev;
      }
    }
    acc0 = __builtin_amdgcn_mfma_f32_16x16x32_bf16(a, b0, acc0, 0, 0, 0);
    acc1 = __builtin_amdgcn_mfma_f32_16x16x32_bf16(a, b1, acc1, 0, 0, 0);
  }
  int bq = quad * 4;
#pragma unroll
  for (int r = 0; r < 4; ++r) {
    C3[(unsigned)mode * 2048u + (bq + r) * 128 + nt0 * 16 + nlo] = f2bf(acc0[r]);
    C3[(unsigned)mode * 2048u + (bq + r) * 128 + (nt0 + 1) * 16 + nlo] = f2bf(acc1[r]);
  }
}

// ---------- transpose 2 (LDS-tiled): C3[mode][b][nc] -> X3t[bo][kx][kk] ----------
__global__ void k_t2(unsigned short* ws) {
  __shared__ unsigned short lds[2 * 63 * 132]; // [bloc(2)][ky(63)] rows x 128 nc, pad 132
  const unsigned short* C3 = ws + C3_O;
  unsigned short* X3t = ws + X3T_O;
  int kx = blockIdx.x >> 3, b0 = (blockIdx.x & 7) * 2;
  int t = threadIdx.x;
#pragma unroll
  for (int it = 0; it < 8; ++it) {
    int g = it * 256 + t;
    if (g < 2016) {
      int flat = g * 8;                       // [ky(63)][bloc(2)][nc(128)]
      int ky = flat >> 8, bloc = (flat >> 7) & 1, nc0 = flat & 127;
      const uint2* src2 = (const uint2*)(C3 + (unsigned)(ky * 32 + kx) * 2048u
                                            + (b0 + bloc) * 128 + nc0);
      uint2* d2 = (uint2*)(lds + (bloc * 63 + ky) * 132 + nc0);
      d2[0] = src2[0]; d2[1] = src2[1];
    }
  }
  __syncthreads();
#pragma unroll
  for (int it = 0; it < 8; ++it) {
    int flat = (it * 256 + t) * 8;            // [bloc(2)][o(64)][kk(128)]
    int bloc = flat >> 13, o = (flat >> 7) & 63, kk0 = flat & 127;
    unsigned short outv[8];
#pragma unroll
    for (int j = 0; j < 8; ++j) {
      int kk = kk0 + j;
      unsigned short v = 0;
      if (kk < 63)        v = lds[(bloc * 63 + kk) * 132 + o];
      else if (kk < 126)  v = lds[(bloc * 63 + (kk - 63)) * 132 + 64 + o];
      outv[j] = v;
    }
    int bo = (b0 + bloc) * 64 + o;
    *(uint4*)(X3t + (unsigned)bo * 4096u + kx * 128 + kk0) = *(uint4*)outv;
  }
}

// ---------- stage 4+5 fused: Y1 = T4 (512x128) * X3t[bo] (128x32) in LDS;
//            out = Y1-rows (128x64) * F5 (64x256), 4 subtiles per bo ----------
__global__ void __launch_bounds__(256) k_s45(unsigned short* ws, float* __restrict__ out) {
  __shared__ unsigned short F5s[16384];
  __shared__ unsigned short Y1s[512 * 36];    // stride 36 bf16: writes conflict-free, reads ~4-way
  const unsigned short* T4f = ws + T4F_O;
  const unsigned short* X3t = ws + X3T_O;
  const unsigned short* F5g = ws + F5F_O;
  int t = threadIdx.x, lane = t & 63, w = t >> 6, quad = lane >> 4, nlo = lane & 15;
  int bo = blockIdx.x;
#pragma unroll
  for (int q = 0; q < 8; ++q)
    ((uint4*)F5s)[q * 256 + t] = ((const uint4*)F5g)[q * 256 + t];
  // ---- s4 phase ----
  int mt0 = w * 8;
  facc4 acc[8][2];
#pragma unroll
  for (int ii = 0; ii < 8; ++ii)
#pragma unroll
    for (int bb = 0; bb < 2; ++bb) acc[ii][bb] = (facc4){0.f, 0.f, 0.f, 0.f};
  const unsigned short* Bb = X3t + (unsigned)bo * 4096u;
#pragma unroll
  for (int ks = 0; ks < 4; ++ks) {
    bfrag8 b0 = ldf(Bb + nlo * 128 + ks * 32 + quad * 8);
    bfrag8 b1 = ldf(Bb + (16 + nlo) * 128 + ks * 32 + quad * 8);
#pragma unroll
    for (int ml = 0; ml < 8; ++ml) {
      bfrag8 a = ldf(T4f + (((mt0 + ml) * 4 + ks) * 64 + lane) * 8);
      acc[ml][0] = __builtin_amdgcn_mfma_f32_16x16x32_bf16(a, b0, acc[ml][0], 0, 0, 0);
      acc[ml][1] = __builtin_amdgcn_mfma_f32_16x16x32_bf16(a, b1, acc[ml][1], 0, 0, 0);
    }
  }
#pragma unroll
  for (int ml = 0; ml < 8; ++ml)
#pragma unroll
    for (int nt = 0; nt < 2; ++nt) {
      facc4 v = acc[ml][nt];
      int m = (mt0 + ml) * 16 + quad * 4, n = nt * 16 + nlo;
#pragma unroll
      for (int r = 0; r < 4; ++r) Y1s[(m + r) * 36 + n] = f2bf(v[r]);
    }
  __syncthreads();
  // ---- s5 phase: 4 subtiles (y0, x0) ----
  int mt0b = w * 2;
  for (int sub = 0; sub < 4; ++sub) {
    int y0 = (sub >> 1) * 128, nh = sub & 1, x0 = nh * 128;
    facc4 acc5[2][8];
#pragma unroll
    for (int ii = 0; ii < 2; ++ii)
#pragma unroll
      for (int bb = 0; bb < 8; ++bb) acc5[ii][bb] = (facc4){0.f, 0.f, 0.f, 0.f};
#pragma unroll
    for (int ks = 0; ks < 2; ++ks) {
      bfrag8 a0 = ld8u2(Y1s + (ks * 256 + y0 + mt0b * 16 + nlo) * 36 + quad * 8);
      bfrag8 a1 = ld8u2(Y1s + (ks * 256 + y0 + (mt0b + 1) * 16 + nlo) * 36 + quad * 8);
#pragma unroll
      for (int nt = 0; nt < 8; ++nt) {
        bfrag8 b = *(bfrag8*)(F5s + ((ks * 16 + nh * 8 + nt) * 64 + lane) * 8);
        acc5[0][nt] = __builtin_amdgcn_mfma_f32_16x16x32_bf16(a0, b, acc5[0][nt], 0, 0, 0);
        acc5[1][nt] = __builtin_amdgcn_mfma_f32_16x16x32_bf16(a1, b, acc5[1][nt], 0, 0, 0);
      }
    }
    float* ob = out + (size_t)bo * 65536 + (size_t)y0 * 256 + x0;
#pragma unroll
    for (int ml = 0; ml < 2; ++ml)
#pragma unroll
      for (int nt = 0; nt < 8; ++nt) {
        int yr = (mt0b + ml) * 16 + quad * 4, xc = nt * 16 + nlo;
        facc4 v = acc5[ml][nt];
#pragma unroll
        for (int r = 0; r < 4; ++r) ob[(yr + r) * 256 + xc] = v[r];
      }
  }
}

extern "C" void kernel_launch(void* const* d_in, const int* in_sizes, int n_in,
                              void* d_out, int out_size, void* d_ws, size_t ws_size,
                              hipStream_t stream) {
  (void)in_sizes; (void)n_in; (void)out_size; (void)ws_size;
  const float* x   = (const float*)d_in[0];
  const float* y0r = (const float*)d_in[1];
  const float* y0i = (const float*)d_in[2];
  const float* ypr = (const float*)d_in[3];
  const float* ypi = (const float*)d_in[4];
  const float* w00 = (const float*)d_in[5];
  unsigned short* ws = (unsigned short*)d_ws;
  float* out = (float*)d_out;

  k_tables<<<dim3(160),  dim3(256), 0, stream>>>(ws);
  k_wpre  <<<dim3(256),  dim3(256), 0, stream>>>(y0r, y0i, ypr, ypi, w00, ws);
  k_s1    <<<dim3(2048), dim3(256), 0, stream>>>(x, ws);
  k_s2    <<<dim3(1024), dim3(256), 0, stream>>>(ws);
  k_t1    <<<dim3(252),  dim3(256), 0, stream>>>(ws);
  k_s3    <<<dim3(2016), dim3(256), 0, stream>>>(ws);
  k_t2    <<<dim3(256),  dim3(256), 0, stream>>>(ws);
  k_s45   <<<dim3(1024), dim3(256), 0, stream>>>(ws, out);
}

// Round 3
// 609.037 us; speedup vs baseline: 1.0030x; 1.0030x over previous
//
#include <hip/hip_runtime.h>

// SpectralConv2d as bf16-MFMA GEMM stages. B=16, Ci=Co=64, S=256, m1=m2=32 -> 63x32 modes.
// R2: 5-kernel pipeline. s1+s2 fused (X1 panel lives in LDS); t1/t2 transposes folded into
// producer epilogues as direct scatter stores (X2m, X3t). kk=126/127 zero rows via k_wpre.
// R3: resubmit (R2 never benched - infra timeout). One safe tweak: s45 s5-phase A-fragment
// loads hoisted out of the nh loop (they depend only on y0).

typedef __attribute__((ext_vector_type(8))) short bfrag8;   // 8 bf16 = 16B
typedef __attribute__((ext_vector_type(4))) float facc4;    // MFMA accumulator

// ---- workspace layout (bf16-element offsets) ----
#define F1F_O 0u            // [8 ks][4 nt][64 lane][8 j]        16384
#define T2F_O 16384u        // [8 mt][16 ks][64][8]              65536
#define T4F_O 81920u        // [32 mt][4 ks][64][8]              65536
#define F5F_O 147456u       // [2 ks][16 nt][64][8]              16384
#define WTMP_O 163840u      // uint[2016 mode][4096 io] (r|i<<16), wpre -> s3
#define X3T_O 37322752u     // [1024 bo][32 kx][128 kk]          4194304
#define X2M_O 54165504u     // [2016 mode][16 b][128 ic]         4128768

#define TWO_PI_256 0.0245436926f

__device__ __forceinline__ unsigned short f2bf(float f) {
  unsigned u = __float_as_uint(f);
  u += 0x7fffu + ((u >> 16) & 1u);          // RNE
  return (unsigned short)(u >> 16);
}
__device__ __forceinline__ bfrag8 ldf(const unsigned short* p) {
  return *(const bfrag8*)p;
}
// 16B fragment from 8B-aligned LDS (stride-36 rows): two b64 reads
__device__ __forceinline__ bfrag8 ld8u2(const unsigned short* p) {
  union { uint2 u2[2]; bfrag8 f; } v;
  v.u2[0] = *(const uint2*)(p);
  v.u2[1] = *(const uint2*)(p + 4);
  return v.f;
}

// ---------- build constant DFT matrices in fragment-linear layout ----------
__global__ void k_tables(unsigned short* ws) {
  int t = threadIdx.x;
  for (int q = 0; q < 4; ++q) {
    int idx = blockIdx.x * 1024 + q * 256 + t;
    float val = 0.f; unsigned dst;
    if (idx < 16384) {                       // F1f: B[k=x][n], fwd row rDFT, /256
      int u = idx, j = u & 7, lane = (u >> 3) & 63, nt = (u >> 9) & 3, ks = u >> 11;
      int k = ks * 32 + (lane >> 4) * 8 + j, n = nt * 16 + (lane & 15);
      if (n < 32) val =  cosf((float)((k * n) & 255) * TWO_PI_256) * (1.f / 256.f);
      else        val = -sinf((float)((k * (n - 32)) & 255) * TWO_PI_256) * (1.f / 256.f);
      dst = F1F_O + (unsigned)idx;
    } else if (idx < 81920) {                // T2f: A[m][kk], fwd col DFT (real form)
      int u = idx - 16384, j = u & 7, lane = (u >> 3) & 63, ks = (u >> 9) & 15, mt = u >> 13;
      int m = mt * 16 + (lane & 15), k = ks * 32 + (lane >> 4) * 8 + j;
      if (m < 126) {
        int ky = m < 63 ? m : m - 63;
        int y = k & 255, f = (ky + 225) & 255;
        float ang = (float)((y * f) & 255) * TWO_PI_256;
        float c = cosf(ang), s = sinf(ang);
        val = (m < 63) ? ((k < 256) ? c : s) : ((k < 256) ? -s : c);
      }
      dst = T2F_O + (unsigned)u;
    } else if (idx < 147456) {               // T4f: A[m][kk], inv col DFT
      int u = idx - 81920, j = u & 7, lane = (u >> 3) & 63, ks = (u >> 9) & 3, mt = u >> 11;
      int m = mt * 16 + (lane & 15), k = ks * 32 + (lane >> 4) * 8 + j;
      if (k < 126) {
        int ky = k < 63 ? k : k - 63;
        int y = m & 255, f = (ky + 225) & 255;
        float ang = (float)((y * f) & 255) * TWO_PI_256;
        float c = cosf(ang), s = sinf(ang);
        val = (m < 256) ? ((k < 63) ? c : -s) : ((k < 63) ? s : c);
      }
      dst = T4F_O + (unsigned)u;
    } else {                                 // F5f: B[k][n=x], inv row irDFT, /256
      int u = idx - 147456, j = u & 7, lane = (u >> 3) & 63, nt = (u >> 9) & 15, ks = u >> 13;
      int k = ks * 32 + (lane >> 4) * 8 + j, n = nt * 16 + (lane & 15);
      int kf = k & 31;
      float ang = (float)((kf * n) & 255) * TWO_PI_256;
      if (k < 32) val = ((kf == 0) ? 1.f : 2.f) * cosf(ang) * (1.f / 256.f);
      else        val = (kf == 0) ? 0.f : -2.f * sinf(ang) * (1.f / 256.f);
      dst = F5F_O + (unsigned)u;
    }
    ws[dst] = f2bf(val);
  }
}

// ---------- weight build: coalesced read -> Wtmp[mode][io] packed (r,i); zero X3t tail rows ----------
__global__ void k_wpre(const float* __restrict__ y0r, const float* __restrict__ y0i,
                       const float* __restrict__ ypr, const float* __restrict__ ypi,
                       const float* __restrict__ w00, unsigned short* ws) {
  unsigned* Wtmp = (unsigned*)(ws + WTMP_O);
  // zero X3t[bo][kx][kk] for kk in {126,127} (t2 used to write these; s3 scatter skips them)
  {
    unsigned short* X3t = ws + X3T_O;
    int g = blockIdx.x * 256 + threadIdx.x;          // 65536 threads, 1 element each
    int bo = g >> 6, kx = (g >> 1) & 31, kk = 126 + (g & 1);
    X3t[(unsigned)bo * 4096u + kx * 128 + kk] = 0;
  }
  int chunk = blockIdx.x >> 4, kq = blockIdx.x & 15;
  int io = chunk * 256 + threadIdx.x;
  int ky0 = kq * 4, nky = (kq == 15) ? 3 : 4;
  const float* pr = ypr + (size_t)io * 1953 + (size_t)ky0 * 31;
  const float* pi_ = ypi + (size_t)io * 1953 + (size_t)ky0 * 31;
  for (int q = 0; q < nky; ++q) {
    int ky = ky0 + q;
#pragma unroll
    for (int kxs = 0; kxs < 31; ++kxs) {
      float r = pr[q * 31 + kxs], im = pi_[q * 31 + kxs];
      Wtmp[(unsigned)(ky * 32 + kxs + 1) * 4096u + io] =
          (unsigned)f2bf(r) | ((unsigned)f2bf(im) << 16);
    }
  }
  if (kq == 0) {                             // col0: y0 / w00 / conj(flip(y0))
    float rr[31], ii[31];
#pragma unroll
    for (int j = 0; j < 31; ++j) { rr[j] = y0r[io * 31 + j]; ii[j] = y0i[io * 31 + j]; }
    float w0 = w00[io];
    for (int ky = 0; ky < 63; ++ky) {
      float r, im;
      if (ky < 31)       { r = rr[ky];      im = ii[ky]; }
      else if (ky == 31) { r = w0;          im = 0.f; }
      else               { r = rr[62 - ky]; im = -ii[62 - ky]; }
      Wtmp[(unsigned)(ky * 32) * 4096u + io] =
          (unsigned)f2bf(r) | ((unsigned)f2bf(im) << 16);
    }
  }
}

// ---------- stage 1+2 fused: per bi, row rDFT into LDS panel, then col DFT, scatter to X2m ----
// phase A (x2): C1 = bf16(x rows) (128x256) * F1 (256x64) -> X1ls[n(32)][kk(512)] (LDS, stride 528)
// phase C:      C2 = T2 (126x512) * X1ls (512x32), epilogue scatters into X2m[mode][b][ic]
__global__ void __launch_bounds__(256) k_s12(const float* __restrict__ x, unsigned short* ws) {
  __shared__ unsigned short F1s[16384];
  __shared__ unsigned short As[128 * 40];     // pad 32->40 (16B-aligned rows, conflict-free)
  __shared__ unsigned short X1ls[32 * 528];   // [n][kk=h*256+y], stride 528 (16B-aligned, ~4-way)
  const unsigned short* F1g = ws + F1F_O;
  const unsigned short* T2f = ws + T2F_O;
  unsigned short* X2m = ws + X2M_O;
  int t = threadIdx.x;
  int bi = blockIdx.x;
  int b = bi >> 6, ii = bi & 63;
#pragma unroll
  for (int q = 0; q < 8; ++q)
    ((uint4*)F1s)[q * 256 + t] = ((const uint4*)F1g)[q * 256 + t];
  int lane = t & 63, w = t >> 6, quad = lane >> 4, nlo = lane & 15;
  int mt0 = w * 2;
  // ---- phase A: two 128-row halves, results into X1ls ----
  for (int y0 = 0; y0 < 256; y0 += 128) {
    facc4 acc[2][4];
#pragma unroll
    for (int a = 0; a < 2; ++a)
#pragma unroll
      for (int bb = 0; bb < 4; ++bb) acc[a][bb] = (facc4){0.f, 0.f, 0.f, 0.f};
    const float* img = x + (size_t)bi * 65536 + (size_t)y0 * 256;
    for (int ks = 0; ks < 8; ++ks) {
      __syncthreads();
#pragma unroll
      for (int q = 0; q < 4; ++q) {           // stage 128x32 fp32 -> bf16 LDS
        int flat = q * 1024 + t * 4;
        int r = flat >> 5, cc = flat & 31;
        float4 v = *(const float4*)(img + r * 256 + ks * 32 + cc);
        unsigned short b4[4] = { f2bf(v.x), f2bf(v.y), f2bf(v.z), f2bf(v.w) };
        *(uint2*)(As + r * 40 + cc) = *(uint2*)b4;
      }
      __syncthreads();
      bfrag8 a0 = *(bfrag8*)(As + (mt0 * 16 + nlo) * 40 + quad * 8);
      bfrag8 a1 = *(bfrag8*)(As + ((mt0 + 1) * 16 + nlo) * 40 + quad * 8);
#pragma unroll
      for (int nt = 0; nt < 4; ++nt) {
        bfrag8 bfr = *(bfrag8*)(F1s + ((ks * 4 + nt) * 64 + lane) * 8);
        acc[0][nt] = __builtin_amdgcn_mfma_f32_16x16x32_bf16(a0, bfr, acc[0][nt], 0, 0, 0);
        acc[1][nt] = __builtin_amdgcn_mfma_f32_16x16x32_bf16(a1, bfr, acc[1][nt], 0, 0, 0);
      }
    }
#pragma unroll
    for (int ml = 0; ml < 2; ++ml)
#pragma unroll
      for (int nt = 0; nt < 4; ++nt) {
        facc4 v = acc[ml][nt];
        int ccol = nt * 16 + nlo, n = ccol & 31, half = ccol >> 5;
        int yrow = y0 + (mt0 + ml) * 16 + quad * 4;
        unsigned short pk[4] = { f2bf(v[0]), f2bf(v[1]), f2bf(v[2]), f2bf(v[3]) };
        *(uint2*)(X1ls + n * 528 + half * 256 + yrow) = *(uint2*)pk;
      }
  }
  __syncthreads();
  // ---- phase C: C2 = T2 * X1ls, scatter epilogue ----
  facc4 c2[2][2];
#pragma unroll
  for (int a = 0; a < 2; ++a)
#pragma unroll
    for (int bb = 0; bb < 2; ++bb) c2[a][bb] = (facc4){0.f, 0.f, 0.f, 0.f};
  for (int ks = 0; ks < 16; ++ks) {
    bfrag8 a0 = ldf(T2f + ((mt0 * 16 + ks) * 64 + lane) * 8);
    bfrag8 a1 = ldf(T2f + (((mt0 + 1) * 16 + ks) * 64 + lane) * 8);
    bfrag8 b0 = *(bfrag8*)(X1ls + nlo * 528 + ks * 32 + quad * 8);
    bfrag8 b1 = *(bfrag8*)(X1ls + (16 + nlo) * 528 + ks * 32 + quad * 8);
    c2[0][0] = __builtin_amdgcn_mfma_f32_16x16x32_bf16(a0, b0, c2[0][0], 0, 0, 0);
    c2[0][1] = __builtin_amdgcn_mfma_f32_16x16x32_bf16(a0, b1, c2[0][1], 0, 0, 0);
    c2[1][0] = __builtin_amdgcn_mfma_f32_16x16x32_bf16(a1, b0, c2[1][0], 0, 0, 0);
    c2[1][1] = __builtin_amdgcn_mfma_f32_16x16x32_bf16(a1, b1, c2[1][1], 0, 0, 0);
  }
#pragma unroll
  for (int ml = 0; ml < 2; ++ml)
#pragma unroll
    for (int nt = 0; nt < 2; ++nt) {
      facc4 v = c2[ml][nt];
      int n = nt * 16 + nlo, mb = (mt0 + ml) * 16 + quad * 4;
#pragma unroll
      for (int r = 0; r < 4; ++r) {
        int m = mb + r;
        if (m < 126) {                        // m=126,127: dead DFT rows (t1 never read them)
          int hf = (m >= 63) ? 1 : 0, ky = m - hf * 63;
          X2m[(unsigned)(ky * 32 + n) * 2048u + b * 128 + hf * 64 + ii] = f2bf(v[r]);
        }
      }
    }
}

// ---------- stage 3 (fused wexp): per mode, X2m (16x128) * expand(Wtmp) (128x128) -> scatter X3t ----
__global__ void k_s3(unsigned short* ws) {
  __shared__ unsigned lds[64 * 65];           // [i][o] pad 64->65: conflict-free
  const unsigned short* X2m = ws + X2M_O;
  const unsigned* Wtmp = (const unsigned*)(ws + WTMP_O);
  unsigned short* X3t = ws + X3T_O;
  int t = threadIdx.x, lane = t & 63, w = t >> 6, quad = lane >> 4, nlo = lane & 15;
  int nt0 = w * 2;
  int mode = blockIdx.x;
  int kyM = mode >> 5, kxM = mode & 31;
#pragma unroll
  for (int q = 0; q < 4; ++q) {               // stage 16KB packed weights, coalesced
    int io = q * 1024 + t * 4;
    uint4 vv = *(const uint4*)(Wtmp + (unsigned)mode * 4096u + io);
    unsigned base = (unsigned)(io >> 6) * 65u + (io & 63);
    lds[base] = vv.x; lds[base + 1] = vv.y; lds[base + 2] = vv.z; lds[base + 3] = vv.w;
  }
  __syncthreads();
  facc4 acc0 = (facc4){0.f, 0.f, 0.f, 0.f}, acc1 = acc0;
  const unsigned short* Am = X2m + (unsigned)mode * 2048u;
#pragma unroll
  for (int ks = 0; ks < 4; ++ks) {            // B[k][n] = [[R,I],[-I,R]] quadrants of W
    bfrag8 a = ldf(Am + nlo * 128 + ks * 32 + quad * 8);
    bfrag8 b0, b1;
#pragma unroll
    for (int f = 0; f < 2; ++f) {
      int n = (nt0 + f) * 16 + nlo, o = n & 63, oh = n >> 6;   // oh wave-uniform
#pragma unroll
      for (int j = 0; j < 8; ++j) {
        int i = (ks & 1) * 32 + quad * 8 + j;                  // i = k & 63; kh = ks>>1
        unsigned pk = lds[i * 65 + o];
        unsigned short re = (unsigned short)(pk & 0xffffu);
        unsigned short im = (unsigned short)(pk >> 16);
        unsigned short ev = (ks < 2) ? (oh == 0 ? re : im)
                                     : (oh == 0 ? (unsigned short)(im ^ 0x8000u) : re);
        if (f == 0) b0[j] = (short)ev; else b1[j] = (short)ev;
      }
    }
    acc0 = __builtin_amdgcn_mfma_f32_16x16x32_bf16(a, b0, acc0, 0, 0, 0);
    acc1 = __builtin_amdgcn_mfma_f32_16x16x32_bf16(a, b1, acc1, 0, 0, 0);
  }
  int bq = quad * 4;
#pragma unroll
  for (int r = 0; r < 4; ++r) {
    int bb = bq + r;
    {
      int nc = nt0 * 16 + nlo, o = nc & 63, hf = nc >> 6;
      X3t[(unsigned)(bb * 64 + o) * 4096u + kxM * 128 + hf * 63 + kyM] = f2bf(acc0[r]);
    }
    {
      int nc = (nt0 + 1) * 16 + nlo, o = nc & 63, hf = nc >> 6;
      X3t[(unsigned)(bb * 64 + o) * 4096u + kxM * 128 + hf * 63 + kyM] = f2bf(acc1[r]);
    }
  }
}

// ---------- stage 4+5 fused: Y1 = T4 (512x128) * X3t[bo] (128x32) in LDS;
//            out = Y1-rows (128x64) * F5 (64x256), 4 subtiles per bo ----------
__global__ void __launch_bounds__(256) k_s45(unsigned short* ws, float* __restrict__ out) {
  __shared__ unsigned short F5s[16384];
  __shared__ unsigned short Y1s[512 * 36];    // stride 36 bf16: writes conflict-free, reads ~4-way
  const unsigned short* T4f = ws + T4F_O;
  const unsigned short* X3t = ws + X3T_O;
  const unsigned short* F5g = ws + F5F_O;
  int t = threadIdx.x, lane = t & 63, w = t >> 6, quad = lane >> 4, nlo = lane & 15;
  int bo = blockIdx.x;
#pragma unroll
  for (int q = 0; q < 8; ++q)
    ((uint4*)F5s)[q * 256 + t] = ((const uint4*)F5g)[q * 256 + t];
  // ---- s4 phase ----
  int mt0 = w * 8;
  facc4 acc[8][2];
#pragma unroll
  for (int a = 0; a < 8; ++a)
#pragma unroll
    for (int bb = 0; bb < 2; ++bb) acc[a][bb] = (facc4){0.f, 0.f, 0.f, 0.f};
  const unsigned short* Bb = X3t + (unsigned)bo * 4096u;
#pragma unroll
  for (int ks = 0; ks < 4; ++ks) {
    bfrag8 b0 = ldf(Bb + nlo * 128 + ks * 32 + quad * 8);
    bfrag8 b1 = ldf(Bb + (16 + nlo) * 128 + ks * 32 + quad * 8);
#pragma unroll
    for (int ml = 0; ml < 8; ++ml) {
      bfrag8 a = ldf(T4f + (((mt0 + ml) * 4 + ks) * 64 + lane) * 8);
      acc[ml][0] = __builtin_amdgcn_mfma_f32_16x16x32_bf16(a, b0, acc[ml][0], 0, 0, 0);
      acc[ml][1] = __builtin_amdgcn_mfma_f32_16x16x32_bf16(a, b1, acc[ml][1], 0, 0, 0);
    }
  }
#pragma unroll
  for (int ml = 0; ml < 8; ++ml)
#pragma unroll
    for (int nt = 0; nt < 2; ++nt) {
      facc4 v = acc[ml][nt];
      int m = (mt0 + ml) * 16 + quad * 4, n = nt * 16 + nlo;
#pragma unroll
      for (int r = 0; r < 4; ++r) Y1s[(m + r) * 36 + n] = f2bf(v[r]);
    }
  __syncthreads();
  // ---- s5 phase: 2 row-halves x 2 col-halves; A-frags hoisted (depend only on y0) ----
  int mt0b = w * 2;
  for (int yh = 0; yh < 2; ++yh) {
    int y0 = yh * 128;
    bfrag8 a0[2], a1[2];
#pragma unroll
    for (int ks = 0; ks < 2; ++ks) {
      a0[ks] = ld8u2(Y1s + (ks * 256 + y0 + mt0b * 16 + nlo) * 36 + quad * 8);
      a1[ks] = ld8u2(Y1s + (ks * 256 + y0 + (mt0b + 1) * 16 + nlo) * 36 + quad * 8);
    }
    for (int nh = 0; nh < 2; ++nh) {
      int x0 = nh * 128;
      facc4 acc5[2][8];
#pragma unroll
      for (int a = 0; a < 2; ++a)
#pragma unroll
        for (int bb = 0; bb < 8; ++bb) acc5[a][bb] = (facc4){0.f, 0.f, 0.f, 0.f};
#pragma unroll
      for (int ks = 0; ks < 2; ++ks) {
#pragma unroll
        for (int nt = 0; nt < 8; ++nt) {
          bfrag8 bfr = *(bfrag8*)(F5s + ((ks * 16 + nh * 8 + nt) * 64 + lane) * 8);
          acc5[0][nt] = __builtin_amdgcn_mfma_f32_16x16x32_bf16(a0[ks], bfr, acc5[0][nt], 0, 0, 0);
          acc5[1][nt] = __builtin_amdgcn_mfma_f32_16x16x32_bf16(a1[ks], bfr, acc5[1][nt], 0, 0, 0);
        }
      }
      float* ob = out + (size_t)bo * 65536 + (size_t)y0 * 256 + x0;
#pragma unroll
      for (int ml = 0; ml < 2; ++ml)
#pragma unroll
        for (int nt = 0; nt < 8; ++nt) {
          int yr = (mt0b + ml) * 16 + quad * 4, xc = nt * 16 + nlo;
          facc4 v = acc5[ml][nt];
#pragma unroll
          for (int r = 0; r < 4; ++r) ob[(yr + r) * 256 + xc] = v[r];
        }
    }
  }
}

extern "C" void kernel_launch(void* const* d_in, const int* in_sizes, int n_in,
                              void* d_out, int out_size, void* d_ws, size_t ws_size,
                              hipStream_t stream) {
  (void)in_sizes; (void)n_in; (void)out_size; (void)ws_size;
  const float* x   = (const float*)d_in[0];
  const float* y0r = (const float*)d_in[1];
  const float* y0i = (const float*)d_in[2];
  const float* ypr = (const float*)d_in[3];
  const float* ypi = (const float*)d_in[4];
  const float* w00 = (const float*)d_in[5];
  unsigned short* ws = (unsigned short*)d_ws;
  float* out = (float*)d_out;

  k_tables<<<dim3(160),  dim3(256), 0, stream>>>(ws);
  k_wpre  <<<dim3(256),  dim3(256), 0, stream>>>(y0r, y0i, ypr, ypi, w00, ws);
  k_s12   <<<dim3(1024), dim3(256), 0, stream>>>(x, ws);
  k_s3    <<<dim3(2016), dim3(256), 0, stream>>>(ws);
  k_s45   <<<dim3(1024), dim3(256), 0, stream>>>(ws, out);
}